// Round 1
// baseline (176.757 us; speedup 1.0000x reference)
//
#include <hip/hip_runtime.h>
#include <hip/hip_fp16.h>
#include <cmath>

// Problem constants: (N,C,H,W) = (16,3,512,512), fp32
#define PLANE (512*512)          // 262144
#define NPLANES 48               // N*C
#define NEL (48*PLANE)           // 12582912

struct Taps { float k[9]; };
struct CMat { float w[3][3]; };   // C-axis 9-tap blur collapsed to 3x3 matrix

// ws layout (uint = packed (E,G) __half2, TILED):
//   idx(q, h, w) = ((h*8 + (w>>6))*48 + q)*64 + (w&63)     q = plane 0..47
//   wsS[0 .. NEL) : HW-blurred log pairs (E in lo half, G in hi half)
//   wsI[0 .. NEL) : (I + 1e-6) pairs, same order
// Total 2*NEL uints = 100.7 MB.  k_cn_loss touches ONLY ws (L2/L3-warm).

#define FOLD(r) ((r) < 0 ? (-1 - (r)) : ((r) > 511 ? (1023 - (r)) : (r)))

// ---------------------------------------------------------------------------
// Kernel 1: fused log + W-blur + H-blur + I staging for BOTH images at once.
// 2-wave block (128 thr) covers a full 512-col row span of one (E,G) plane
// pair, 16-row strip. W-window distribution via LDS row buffer (double-
// buffered, 1 barrier/row): kills the 12 shuffles, 4 halo-log issues, halo
// global loads and edge cndmasks of the previous version. Ring packs (E,G)
// per col as half2 so H-blur pk-fma covers both images and the store is a
// ready-made dwordx4. grid (32, 48), block 128.
// ---------------------------------------------------------------------------
__global__ __launch_bounds__(128)
void k_blur_hw(const float* __restrict__ inE, const float* __restrict__ inG,
               uint* __restrict__ wsS, uint* __restrict__ wsI, Taps tp)
{
    const int g  = threadIdx.x;               // 0..127 -> cols 4g..4g+3
    const int r0 = blockIdx.x * 16;           // 32 rowgroups
    const int z  = blockIdx.y;                // plane pair 0..47
    const float* __restrict__ srcE = inE + z * PLANE;
    const float* __restrict__ srcG = inG + z * PLANE;
    const int col   = 4 * g;
    const int tile  = col >> 6;
    const int inner = col & 63;
    const bool edge = (g == 0) || (g == 127);
    const int  eoff = (g == 0) ? 0 : 516;     // reflected halo slot

    // buf[parity][img][4 + 512 + 4] : logged row, halo via reflection
    __shared__ float buf[2][2][520];

    __half2 kh[9];
#pragma unroll
    for (int t = 0; t < 9; ++t) kh[t] = __float2half2_rn(tp.k[t]);

    __half2 ring[12][4];                      // W-blurred rows, (E,G) per col

    float4 pE[3], pG[3];                      // depth-3 load pipeline
#pragma unroll
    for (int s = 0; s < 3; ++s) {
        const int row = FOLD(r0 - 4 + s);
        pE[s] = *(const float4*)(srcE + row * 512 + col);
        pG[s] = *(const float4*)(srcG + row * 512 + col);
    }

#pragma unroll
    for (int jb = 0; jb < 24; jb += 12) {
#pragma unroll
        for (int u = 0; u < 12; ++u) {
            const int j   = jb + u;           // input row r0-4+j
            const int par = j & 1;

            float4 oe = pE[0], og = pG[0];
            pE[0] = pE[1]; pE[1] = pE[2];
            pG[0] = pG[1]; pG[1] = pG[2];
            if (j + 3 < 24) {                 // load row j+3
                const int row = FOLD(r0 - 1 + j);
                pE[2] = *(const float4*)(srcE + row * 512 + col);
                pG[2] = *(const float4*)(srcG + row * 512 + col);
            }

            const float e4 = __logf(oe.x + 1e-6f);
            const float e5 = __logf(oe.y + 1e-6f);
            const float e6 = __logf(oe.z + 1e-6f);
            const float e7 = __logf(oe.w + 1e-6f);
            const float g4 = __logf(og.x + 1e-6f);
            const float g5 = __logf(og.y + 1e-6f);
            const float g6 = __logf(og.z + 1e-6f);
            const float g7 = __logf(og.w + 1e-6f);

            *(float4*)&buf[par][0][4 + col] = make_float4(e4, e5, e6, e7);
            *(float4*)&buf[par][1][4 + col] = make_float4(g4, g5, g6, g7);
            if (edge) {                       // symmetric reflect at image edge
                *(float4*)&buf[par][0][eoff] = make_float4(e7, e6, e5, e4);
                *(float4*)&buf[par][1][eoff] = make_float4(g7, g6, g5, g4);
            }

            // stage (I+eps) pairs for center rows while the write drains
            if (j >= 4 && j < 20) {
                const int ri = r0 + j - 4;
                __half2 i0 = __floats2half2_rn(oe.x + 1e-6f, og.x + 1e-6f);
                __half2 i1 = __floats2half2_rn(oe.y + 1e-6f, og.y + 1e-6f);
                __half2 i2 = __floats2half2_rn(oe.z + 1e-6f, og.z + 1e-6f);
                __half2 i3 = __floats2half2_rn(oe.w + 1e-6f, og.w + 1e-6f);
                uint* dp = wsI + (((ri * 8 + tile) * 48) + z) * 64 + inner;
                *(uint4*)dp = make_uint4(*(uint*)&i0, *(uint*)&i1,
                                         *(uint*)&i2, *(uint*)&i3);
            }

            __syncthreads();                  // buf[par] complete

            // W-blur E (fp32), window = LDS halo quads + own registers
            float oE0, oE1, oE2, oE3, oG0, oG1, oG2, oG3;
            {
                float4 lA = *(const float4*)&buf[par][0][col];      // col-4..col-1
                float4 lB = *(const float4*)&buf[par][0][col + 8];  // col+4..col+7
                float wv[12] = {lA.x, lA.y, lA.z, lA.w, e4, e5, e6, e7,
                                lB.x, lB.y, lB.z, lB.w};
                float o0 = 0.f, o1 = 0.f, o2 = 0.f, o3 = 0.f;
#pragma unroll
                for (int t = 0; t < 9; ++t) {
                    const float kt = tp.k[t];
                    o0 += kt * wv[t];
                    o1 += kt * wv[t + 1];
                    o2 += kt * wv[t + 2];
                    o3 += kt * wv[t + 3];
                }
                oE0 = o0; oE1 = o1; oE2 = o2; oE3 = o3;
            }
            // W-blur G
            {
                float4 lA = *(const float4*)&buf[par][1][col];
                float4 lB = *(const float4*)&buf[par][1][col + 8];
                float wv[12] = {lA.x, lA.y, lA.z, lA.w, g4, g5, g6, g7,
                                lB.x, lB.y, lB.z, lB.w};
                float o0 = 0.f, o1 = 0.f, o2 = 0.f, o3 = 0.f;
#pragma unroll
                for (int t = 0; t < 9; ++t) {
                    const float kt = tp.k[t];
                    o0 += kt * wv[t];
                    o1 += kt * wv[t + 1];
                    o2 += kt * wv[t + 2];
                    o3 += kt * wv[t + 3];
                }
                oG0 = o0; oG1 = o1; oG2 = o2; oG3 = o3;
            }
            ring[u][0] = __floats2half2_rn(oE0, oG0);
            ring[u][1] = __floats2half2_rn(oE1, oG1);
            ring[u][2] = __floats2half2_rn(oE2, oG2);
            ring[u][3] = __floats2half2_rn(oE3, oG3);

            // H-blur (packed (E,G) fp16) + store once 9 rows live
            if (j >= 8) {
                __half2 a0 = __float2half2_rn(0.f), a1 = a0, a2 = a0, a3 = a0;
#pragma unroll
                for (int t = 0; t < 9; ++t) {
                    const int sl = (j - 8 + t) % 12;     // compile-time
                    a0 = __hfma2(kh[t], ring[sl][0], a0);
                    a1 = __hfma2(kh[t], ring[sl][1], a1);
                    a2 = __hfma2(kh[t], ring[sl][2], a2);
                    a3 = __hfma2(kh[t], ring[sl][3], a3);
                }
                const int ro = r0 + j - 8;
                uint* dp = wsS + (((ro * 8 + tile) * 48) + z) * 64 + inner;
                *(uint4*)dp = make_uint4(*(uint*)&a0, *(uint*)&a1,
                                         *(uint*)&a2, *(uint*)&a3);
            }
        }
    }
}

// ---------------------------------------------------------------------------
// Kernel 2: C-blur + N-blur + loss. ONE (h,w) point per thread; the half2
// lanes carry (E,G) of that point, so every pk-fma serves both images and
// the loads per thread halve vs the point-pair version. 2x the waves
// (4096, 16/CU) for the latency-bound ws reads.
// grid (1024), block (256).
// ---------------------------------------------------------------------------
__global__ __launch_bounds__(256)
void k_cn_loss(const uint* __restrict__ wsS, const uint* __restrict__ wsI,
               float* __restrict__ out, Taps tp, CMat cm)
{
    const int tid = threadIdx.x;
    const int p   = blockIdx.x * 256 + tid;      // point index 0..262143
    const int w   = p & 511;
    const int h   = p >> 9;
    const int base = ((h * 8 + (w >> 6)) * 48) * 64 + (w & 63);
    const uint* __restrict__ sb = wsS + base;
    const uint* __restrict__ ib = wsI + base;
    // plane q at +q*64

    __half2 k2[9], cw[3][3];
#pragma unroll
    for (int t = 0; t < 9; ++t) k2[t] = __float2half2_rn(tp.k[t]);
#pragma unroll
    for (int i = 0; i < 3; ++i)
#pragma unroll
        for (int jj = 0; jj < 3; ++jj) cw[i][jj] = __float2half2_rn(cm.w[i][jj]);

    __half2 r[9][3];                             // C-blurred (E,G), slot = m % 9

#define LOADS(m, u)                                                            \
    u[0] = sb[((m) * 3 + 0) * 64];                                             \
    u[1] = sb[((m) * 3 + 1) * 64];                                             \
    u[2] = sb[((m) * 3 + 2) * 64];

#define CBLUR(u, d)                                                            \
    {                                                                          \
        __half2 v0 = *(__half2*)&u[0];                                         \
        __half2 v1 = *(__half2*)&u[1];                                         \
        __half2 v2 = *(__half2*)&u[2];                                         \
        d[0] = __hfma2(cw[0][0], v0, __hfma2(cw[0][1], v1, __hmul2(cw[0][2], v2))); \
        d[1] = __hfma2(cw[1][0], v0, __hfma2(cw[1][1], v1, __hmul2(cw[1][2], v2))); \
        d[2] = __hfma2(cw[2][0], v0, __hfma2(cw[2][1], v1, __hmul2(cw[2][2], v2))); \
    }

    {
        uint su[3];
#pragma unroll
        for (int m = 0; m < 4; ++m) { LOADS(m, su); CBLUR(su, r[m]); }
    }
    uint nu[3];
    LOADS(4, nu);
    uint iu[3];
    iu[0] = ib[0]; iu[1] = ib[64]; iu[2] = ib[128];

    float acc = 0.f;
#pragma unroll
    for (int n = 0; n < 16; ++n) {
        uint niu[3];
        if (n + 1 < 16) {
#pragma unroll
            for (int c = 0; c < 3; ++c) niu[c] = ib[((n + 1) * 3 + c) * 64];
        }
        const int mnew = n + 4;
        if (mnew < 16) {
            CBLUR(nu, r[mnew % 9]);
            if (mnew + 1 < 16) { LOADS(mnew + 1, nu); }
        }
#pragma unroll
        for (int c = 0; c < 3; ++c) {
            __half2 s2 = __float2half2_rn(0.f);
#pragma unroll
            for (int t = 0; t < 9; ++t) {
                int m = n - 4 + t;
                m = (m < 0) ? (-1 - m) : ((m > 15) ? (31 - m) : m);  // compile-time
                s2 = __hfma2(k2[t], r[m % 9][c], s2);
            }
            const float2 sf  = __half22float2(s2);
            const float2 if2 = __half22float2(*(__half2*)&iu[c]);

            float eE = __expf(-sf.x), eG = __expf(-sf.y);
            float Re = if2.x * eE;
            float Rg = if2.y * eG;
            float Le = __builtin_amdgcn_rcpf(eE);
            float Lg = __builtin_amdgcn_rcpf(eG);
            float dr = Re - Rg, dl = Le - Lg;
            acc += dr * dr + dl * dl;
        }
        if (n + 1 < 16) { iu[0] = niu[0]; iu[1] = niu[1]; iu[2] = niu[2]; }
    }
#undef LOADS
#undef CBLUR

    __shared__ float red[256];
    red[tid] = acc;
    __syncthreads();
#pragma unroll
    for (int s = 128; s > 0; s >>= 1) {
        if (tid < s) red[tid] += red[tid + s];
        __syncthreads();
    }
    if (tid == 0) atomicAdd(out, red[0] * (1.0f / (float)NEL));
}

extern "C" void kernel_launch(void* const* d_in, const int* in_sizes, int n_in,
                              void* d_out, int out_size, void* d_ws, size_t ws_size,
                              hipStream_t stream) {
    const float* Ie = (const float*)d_in[0];
    const float* Ig = (const float*)d_in[1];

    // Gaussian taps: sigma=1, radius=int(4*1+0.5)=4, double-precision normalize
    Taps tp;
    {
        double kk[9], s = 0.0;
        for (int i = 0; i < 9; ++i) { double x = (double)(i - 4); kk[i] = exp(-0.5 * x * x); s += kk[i]; }
        for (int i = 0; i < 9; ++i) tp.k[i] = (float)(kk[i] / s);
    }

    // C-axis (size 3) 9-tap symmetric blur collapsed to a 3x3 matrix
    CMat cm;
    {
        for (int c = 0; c < 3; ++c) {
            cm.w[c][0] = cm.w[c][1] = cm.w[c][2] = 0.f;
            for (int t = 0; t < 9; ++t) {
                int m = c - 4 + t;
                int mm = ((m % 6) + 6) % 6;          // symmetric reflect, period 6
                if (mm > 2) mm = 5 - mm;
                cm.w[c][mm] += tp.k[t];
            }
        }
    }

    uint* wsS = (uint*)d_ws;                     // packed (E,G) blurred logs
    uint* wsI = wsS + (size_t)NEL;               // packed (E,G) (I+eps)

    hipMemsetAsync(d_out, 0, sizeof(float), stream);  // zero the atomic target
    dim3 g1(32, 48);
    k_blur_hw<<<g1, 128, 0, stream>>>(Ie, Ig, wsS, wsI, tp);
    k_cn_loss<<<1024, 256, 0, stream>>>(wsS, wsI, (float*)d_out, tp, cm);
}